// Round 8
// baseline (531.477 us; speedup 1.0000x reference)
//
#include <hip/hip_runtime.h>

// GSA layer: q/k/v = x@Wqkv^T+b ; row+col attention with -gw*(i-j)^2 bias ; out = (r+c)@Wo^T+bo
// fp16 MFMA pipeline (fp32 accum, fp32 softmax).
// GEMM: 256x256 tile, BK=64, 8 waves, T1 XCD swizzle, T2 LDS XOR swizzle, T5.
// r8: (a) mfma 32x32x16 (halves MFMA instr count, +11% ubench rate vs 16x16),
//     (b) running stage pointers (kill per-tile 64-bit addr rebuild VALU).
// r7 lesson: barrier count is NOT the limiter (8->2 barriers was neutral);
// per-wave serial issue work is (2 waves/SIMD, VGPR-capped).

typedef _Float16 f16;
typedef __attribute__((ext_vector_type(8))) _Float16 f16x8;
typedef __attribute__((ext_vector_type(4))) float f32x4;
typedef __attribute__((ext_vector_type(16))) float f32x16;

// ------------- fused f32 -> f16 convert: x + Wq/Wk/Wv/Wo in one launch ------
__global__ __launch_bounds__(256) void k_cvt_all(
    const float* __restrict__ x, const float* __restrict__ Wq,
    const float* __restrict__ Wk, const float* __restrict__ Wv,
    const float* __restrict__ Wo, f16* __restrict__ xb,
    f16* __restrict__ wqkv, f16* __restrict__ wob) {
  const int stride = gridDim.x * blockDim.x;
  const int X8 = 33554432 / 8;
  const int W8 = 1048576 / 8;      // 2^17
  const int total = X8 + 4 * W8;
  for (int i = blockIdx.x * blockDim.x + threadIdx.x; i < total; i += stride) {
    const float* src; f16* dst; int o8;
    if (i < X8) { src = x; dst = xb; o8 = i; }
    else {
      int j = i - X8; int seg = j >> 17; o8 = j & (W8 - 1);
      if (seg == 0)      { src = Wq; dst = wqkv; }
      else if (seg == 1) { src = Wk; dst = wqkv + 1048576; }
      else if (seg == 2) { src = Wv; dst = wqkv + 2097152; }
      else               { src = Wo; dst = wob; }
    }
    const float4* p = (const float4*)src + (size_t)o8 * 2;
    float4 a = p[0]; float4 b = p[1];
    f16x8 o;
    o[0]=(f16)a.x; o[1]=(f16)a.y; o[2]=(f16)a.z; o[3]=(f16)a.w;
    o[4]=(f16)b.x; o[5]=(f16)b.y; o[6]=(f16)b.z; o[7]=(f16)b.w;
    *(f16x8*)(dst + (size_t)o8 * 8) = o;
  }
}

// ---- C[M,N] = A[M,K]*B[N,K]^T + bias; 256^2 tile, BK=64, 8 waves, 32x32x16 ----
// Waves: wr=wid>>2 (2 M-halves), wc=wid&3 (4 N-quarters). Per-wave C: 128x64 =
// 4 m-tiles x 2 n-tiles of 32x32; acc = f32x16[4][2] = 128 AGPR.
// LDS: smem[slot][A/B][half][128*64] = 128 KiB, XOR-swizzled in 16B units.
// K-tile (2 barriers, r7 structure): vmcnt(4)+bar; read B(8)+A_ks0(4);
// lgkm(4)+bar; stage (running ptrs); [MFMA ks | read A ks+1] x4.
template<bool C_F32>
__global__ __launch_bounds__(512, 2) void k_gemm256(const f16* __restrict__ A,
                                                    const f16* __restrict__ B,
                                                    const float* __restrict__ b0,
                                                    const float* __restrict__ b1,
                                                    const float* __restrict__ b2,
                                                    void* __restrict__ Cout,
                                                    int M, int N, int K) {
  __shared__ f16 smem[2][2][2][128 * 64];   // [slot][A/B][half] = 128 KiB

  const int tid = threadIdx.x;
  const int lane = tid & 63;
  const int wid = tid >> 6;
  const int wr = wid >> 2;        // M-half
  const int wc = wid & 3;         // N-quarter
  const int l31 = lane & 31;
  const int l7 = lane & 7;
  const int kh = lane >> 5;       // k-half within 16

  // T1: XCD-aware swizzle (nwg % 8 == 0 by construction)
  const int nwg = gridDim.x;
  const int bid = blockIdx.x;
  const int swz = (bid & 7) * (nwg >> 3) + (bid >> 3);
  const int nbn = N >> 8;
  const int bm = swz / nbn, bn = swz % nbn;

  // swizzled in-row element offsets per k-step: unit = (ks*2 + kh) ^ (row&7),
  // row&7 == lane&7 for both A (m*32+l31) and B (n*32+l31) fragment rows.
  const int uo0 = ((0 + kh) ^ l7) * 8;
  const int uo1 = ((2 + kh) ^ l7) * 8;
  const int uo2 = ((4 + kh) ^ l7) * 8;
  const int uo3 = ((6 + kh) ^ l7) * 8;
  const int uo[4] = {uo0, uo1, uo2, uo3};
  const int bofs = (wc & 1) * 64;

  // staging: lane covers LDS row l>>3, unit l&7; inverse-swizzled global unit
  const size_t soff0 = (size_t)(wid * 16 + (lane >> 3)) * K + ((lane & 7) ^ (lane >> 3)) * 8;
  const size_t soff8 = soff0 + (size_t)8 * K;

  const f16* Ag0 = A + (size_t)(bm * 256) * K;
  const f16* Bg0 = B + (size_t)(bn * 256) * K;
  const size_t HSTRIDE = (size_t)128 * K;

  f32x16 acc[4][2];
#pragma unroll
  for (int m = 0; m < 4; ++m)
#pragma unroll
    for (int n = 0; n < 2; ++n)
#pragma unroll
      for (int r = 0; r < 16; ++r) acc[m][n][r] = 0.f;

#define STAGE2(p, lbase)                                                            \
  {                                                                                 \
    __builtin_amdgcn_global_load_lds(                                               \
        (const __attribute__((address_space(1))) void*)((p) + soff0),               \
        (__attribute__((address_space(3))) void*)((lbase) + (wid * 16) * 64), 16, 0, 0); \
    __builtin_amdgcn_global_load_lds(                                               \
        (const __attribute__((address_space(1))) void*)((p) + soff8),               \
        (__attribute__((address_space(3))) void*)((lbase) + (wid * 16 + 8) * 64), 16, 0, 0); \
  }

#define READ_A32(ks)                                                                \
  _Pragma("unroll") for (int m = 0; m < 4; ++m)                                     \
    afrag[m] = *(const f16x8*)&As_[(m * 32 + l31) * 64 + uo[ks]];

#define MFMA32(ks)                                                                  \
  _Pragma("unroll") for (int m = 0; m < 4; ++m)                                     \
  _Pragma("unroll") for (int n = 0; n < 2; ++n)                                     \
    acc[m][n] = __builtin_amdgcn_mfma_f32_32x32x16_f16(afrag[m], bfrag[n][ks], acc[m][n], 0, 0, 0);

  // vm: vmcnt at tile entry. st: 2 = stage A+B; 1 = A only; 0 = none
#define KTILE(slot, vm, st)                                                         \
  {                                                                                 \
    f16* As_ = smem[slot][0][wr];                                                   \
    f16* Bs_ = smem[slot][1][wc >> 1];                                              \
    f16x8 bfrag[2][4], afrag[4];                                                    \
    asm volatile("s_waitcnt vmcnt(%0)" :: "n"(vm) : "memory");                      \
    __builtin_amdgcn_s_barrier();                                                   \
    _Pragma("unroll") for (int n = 0; n < 2; ++n)                                   \
    _Pragma("unroll") for (int ks = 0; ks < 4; ++ks)                                \
      bfrag[n][ks] = *(const f16x8*)&Bs_[(bofs + n * 32 + l31) * 64 + uo[ks]];      \
    READ_A32(0)                                                                     \
    asm volatile("s_waitcnt lgkmcnt(4)" ::: "memory");                              \
    __builtin_amdgcn_s_barrier();                                                   \
    if ((st) >= 1) {                                                                \
      STAGE2(pA0, smem[(slot) ^ 1][0][0]);                                          \
      STAGE2(pA1, smem[(slot) ^ 1][0][1]);                                          \
      pA0 += 64; pA1 += 64;                                                         \
    }                                                                               \
    if ((st) == 2) {                                                                \
      STAGE2(pB0, smem[slot][1][0]);                                                \
      STAGE2(pB1, smem[slot][1][1]);                                                \
      pB0 += 64; pB1 += 64;                                                         \
    }                                                                               \
    __builtin_amdgcn_s_setprio(1);                                                  \
    MFMA32(0)                                                                       \
    READ_A32(1)                                                                     \
    MFMA32(1)                                                                       \
    READ_A32(2)                                                                     \
    MFMA32(2)                                                                       \
    READ_A32(3)                                                                     \
    MFMA32(3)                                                                       \
    __builtin_amdgcn_s_setprio(0);                                                  \
  }

  const int nt = K >> 6;   // K-tiles (>= 4, even)

  // prologue: A_0 -> s0, B_0 -> s0, B_1 -> s1 (12 gloads; KTILE(0) waits vm4)
  STAGE2(Ag0,                smem[0][0][0]);
  STAGE2(Ag0 + HSTRIDE,      smem[0][0][1]);
  STAGE2(Bg0,                smem[0][1][0]);
  STAGE2(Bg0 + HSTRIDE,      smem[0][1][1]);
  STAGE2(Bg0 + 64,           smem[1][1][0]);
  STAGE2(Bg0 + HSTRIDE + 64, smem[1][1][1]);

  // running stage pointers: A next stages k-tile 1, B next stages k-tile 2
  const f16* pA0 = Ag0 + 64;
  const f16* pA1 = Ag0 + HSTRIDE + 64;
  const f16* pB0 = Bg0 + 128;
  const f16* pB1 = Bg0 + HSTRIDE + 128;

  for (int t = 0; t + 3 < nt; t += 2) {
    KTILE(0, 4, 2)
    KTILE(1, 4, 2)
  }
  KTILE(0, 4, 1)
  KTILE(1, 0, 0)

  // epilogue: 32x32 C/D layout (m74/m101): col = n*32 + (lane&31),
  // row = m*32 + (reg&3) + 8*(reg>>2) + 4*(lane>>5)
  const int mrow0 = bm * 256 + wr * 128;
  const int ncol0 = bn * 256 + wc * 64 + l31;
#pragma unroll
  for (int n = 0; n < 2; ++n) {
    const int col = ncol0 + n * 32;
    const float* bp = (col < 1024) ? b0 : ((col < 2048) ? b1 : b2);
    const float bvv = bp[col & 1023];
#pragma unroll
    for (int m = 0; m < 4; ++m) {
#pragma unroll
      for (int r = 0; r < 16; ++r) {
        const int row = mrow0 + m * 32 + (r & 3) + 8 * (r >> 2) + 4 * kh;
        const float val = acc[m][n][r] + bvv;
        if (C_F32) ((float*)Cout)[(size_t)row * N + col] = val;
        else       ((f16*)Cout)[(size_t)row * N + col] = (f16)val;
      }
    }
  }
#undef KTILE
#undef MFMA32
#undef READ_A32
#undef STAGE2
}

// ------------------- axis attention: one block per (b,line) -----------------
// qkv layout: [32768 tokens][3072] with q at +0, k at +1024, v at +2048.
template<bool IS_COL>
__global__ __launch_bounds__(256) void k_attn(const f16* __restrict__ qkv,
                                              f16* __restrict__ attn,
                                              const float* __restrict__ sigma) {
  __shared__ union { float S[64][68]; f16 Vt[256][72]; } sm;
  __shared__ f16 P[64][72];

  const int tid = threadIdx.x;
  const int lane = tid & 63;
  const int wid = tid >> 6;
  const int blk = blockIdx.x;

  size_t tok0; int tstr;
  if (IS_COL) { tok0 = (size_t)(blk >> 6) * 4096 + (blk & 63); tstr = 64; }
  else        { tok0 = (size_t)blk * 64;                       tstr = 1;  }
  const size_t ibase = tok0 * 3072;  const int istr = tstr * 3072;
  const size_t obase = tok0 * 1024;  const int ostr = tstr * 1024;

  const float sg = sigma[0];
  const float gw = 0.5f / (sg * sg);

  const int m0 = wid * 16;
  const int lr = lane & 15;
  const int lq = lane >> 4;

  // ---- phase A: S = Q K^T ----
  f32x4 sacc[4];
#pragma unroll
  for (int nt = 0; nt < 4; ++nt) sacc[nt] = (f32x4){0.f, 0.f, 0.f, 0.f};
  const f16* qp = qkv + ibase + (size_t)(m0 + lr) * istr + lq * 8;
  const f16* kp = qkv + ibase + 1024 + (size_t)lr * istr + lq * 8;
#pragma unroll 2
  for (int ks = 0; ks < 32; ++ks) {
    f16x8 af = *(const f16x8*)(qp + ks * 32);
#pragma unroll
    for (int nt = 0; nt < 4; ++nt) {
      f16x8 bfr = *(const f16x8*)(kp + (size_t)nt * 16 * istr + ks * 32);
      sacc[nt] = __builtin_amdgcn_mfma_f32_16x16x32_f16(af, bfr, sacc[nt], 0, 0, 0);
    }
  }
#pragma unroll
  for (int nt = 0; nt < 4; ++nt)
#pragma unroll
    for (int r = 0; r < 4; ++r) {
      const int row = m0 + lq * 4 + r;
      const int col = nt * 16 + lr;
      const float dd = (float)(row - col);
      sm.S[row][col] = sacc[nt][r] - gw * dd * dd;
    }
  __syncthreads();

  // ---- phase B: row softmax, 4 threads per row ----
  {
    const int r = tid >> 2, s4 = tid & 3;
    const float4* sp = (const float4*)&sm.S[r][s4 * 16];
    float vals[16];
#pragma unroll
    for (int j = 0; j < 4; ++j) {
      float4 t = sp[j];
      vals[j * 4 + 0] = t.x; vals[j * 4 + 1] = t.y; vals[j * 4 + 2] = t.z; vals[j * 4 + 3] = t.w;
    }
    float mx = vals[0];
#pragma unroll
    for (int j = 1; j < 16; ++j) mx = fmaxf(mx, vals[j]);
    mx = fmaxf(mx, __shfl_xor(mx, 1));
    mx = fmaxf(mx, __shfl_xor(mx, 2));
    float sum = 0.f;
#pragma unroll
    for (int j = 0; j < 16; ++j) { vals[j] = __expf(vals[j] - mx); sum += vals[j]; }
    sum += __shfl_xor(sum, 1);
    sum += __shfl_xor(sum, 2);
    const float inv = 1.f / sum;
#pragma unroll
    for (int j = 0; j < 16; ++j) P[r][s4 * 16 + j] = (f16)(vals[j] * inv);
  }
  __syncthreads();

  // ---- phase C: O = P V ; V transposed through LDS in 256-col chunks ----
  const f16x8 af0 = *(const f16x8*)&P[m0 + lr][lq * 8];
  const f16x8 af1 = *(const f16x8*)&P[m0 + lr][32 + lq * 8];

  const int kr = tid & 63;
  const int cg = tid >> 6;
  const f16* vp = qkv + ibase + 2048 + (size_t)kr * istr;

  for (int c = 0; c < 4; ++c) {
#pragma unroll
    for (int j8 = 0; j8 < 8; ++j8) {
      const int cl = cg * 64 + j8 * 8;
      f16x8 vv = *(const f16x8*)(vp + c * 256 + cl);
#pragma unroll
      for (int e = 0; e < 8; ++e) sm.Vt[cl + e][kr] = vv[e];
    }
    __syncthreads();
#pragma unroll
    for (int nt = 0; nt < 16; ++nt) {
      const f16x8 bf0 = *(const f16x8*)&sm.Vt[nt * 16 + lr][lq * 8];
      const f16x8 bf1 = *(const f16x8*)&sm.Vt[nt * 16 + lr][32 + lq * 8];
      f32x4 o = (f32x4){0.f, 0.f, 0.f, 0.f};
      o = __builtin_amdgcn_mfma_f32_16x16x32_f16(af0, bf0, o, 0, 0, 0);
      o = __builtin_amdgcn_mfma_f32_16x16x32_f16(af1, bf1, o, 0, 0, 0);
#pragma unroll
      for (int r = 0; r < 4; ++r) {
        const int row = m0 + lq * 4 + r;
        const int col = c * 256 + nt * 16 + lr;
        const size_t addr = obase + (size_t)row * ostr + col;
        float val = o[r];
        if (IS_COL) val += (float)attn[addr];
        attn[addr] = (f16)val;
      }
    }
    __syncthreads();
  }
}

extern "C" void kernel_launch(void* const* d_in, const int* in_sizes, int n_in,
                              void* d_out, int out_size, void* d_ws, size_t ws_size,
                              hipStream_t stream) {
  const float* x  = (const float*)d_in[0];
  const float* Wq = (const float*)d_in[1];
  const float* bq = (const float*)d_in[2];
  const float* Wk = (const float*)d_in[3];
  const float* bk = (const float*)d_in[4];
  const float* Wv = (const float*)d_in[5];
  const float* bv = (const float*)d_in[6];
  const float* Wo = (const float*)d_in[7];
  const float* bo = (const float*)d_in[8];
  const float* sg = (const float*)d_in[9];

  const int M = 8 * 64 * 64;          // 32768 tokens
  const size_t NE = (size_t)M * 1024;

  f16* xb   = (f16*)d_ws;             // reused as attn buffer after QKV
  f16* wqkv = xb + NE;                // [3072][1024]
  f16* wob  = wqkv + 3 * 1024 * 1024; // [1024][1024]
  f16* qkv  = wob + 1024 * 1024;      // [32768][3072]

  k_cvt_all<<<2048, 256, 0, stream>>>(x, Wq, Wk, Wv, Wo, xb, wqkv, wob);

  // fused QKV GEMM: [32768,1024] x [3072,1024]^T -> [32768,3072]
  k_gemm256<false><<<(M / 256) * (3072 / 256), 512, 0, stream>>>(
      xb, wqkv, bq, bk, bv, qkv, M, 3072, 1024);

  f16* attn = xb;                     // x_f16 dead after QKV GEMM
  k_attn<false><<<512, 256, 0, stream>>>(qkv, attn, sg);  // row: writes
  k_attn<true><<<512, 256, 0, stream>>>(qkv, attn, sg);   // col: accumulates

  // output GEMM: [32768,1024] x [1024,1024]^T -> f32 out
  k_gemm256<true><<<(M / 256) * (1024 / 256), 512, 0, stream>>>(
      attn, wob, bo, bo, bo, (float*)d_out, M, 1024, 1024);
}

// Round 9
// 500.244 us; speedup vs baseline: 1.0624x; 1.0624x over previous
//
#include <hip/hip_runtime.h>

// GSA layer: q/k/v = x@Wqkv^T+b ; row+col attention with -gw*(i-j)^2 bias ; out = (r+c)@Wo^T+bo
// fp16 MFMA pipeline (fp32 accum, fp32 softmax).
// GEMM: r7-proven (888 TF @ K=1024 = m248 structure ceiling): 256^2 tile, BK=64,
// 8 waves, 2-barrier K-tile, counted vmcnt, T1/T2/T5. r8's 32x32 reverted
// (swizzle is 16x16-pattern-specific: 1.9e7 bank conflicts with 32x32 frags).
// r9 attn: T14 reg-staged V prefetch (chunk c+1 loads in flight under chunk c
// MFMA) + LDS transpose-out epilogue (coalesced 128B stores, fixes col RMW's
// 32B-segment write amplification).

typedef _Float16 f16;
typedef __attribute__((ext_vector_type(8))) _Float16 f16x8;
typedef __attribute__((ext_vector_type(4))) float f32x4;

// ------------- fused f32 -> f16 convert: x + Wq/Wk/Wv/Wo in one launch ------
__global__ __launch_bounds__(256) void k_cvt_all(
    const float* __restrict__ x, const float* __restrict__ Wq,
    const float* __restrict__ Wk, const float* __restrict__ Wv,
    const float* __restrict__ Wo, f16* __restrict__ xb,
    f16* __restrict__ wqkv, f16* __restrict__ wob) {
  const int stride = gridDim.x * blockDim.x;
  const int X8 = 33554432 / 8;
  const int W8 = 1048576 / 8;      // 2^17
  const int total = X8 + 4 * W8;
  for (int i = blockIdx.x * blockDim.x + threadIdx.x; i < total; i += stride) {
    const float* src; f16* dst; int o8;
    if (i < X8) { src = x; dst = xb; o8 = i; }
    else {
      int j = i - X8; int seg = j >> 17; o8 = j & (W8 - 1);
      if (seg == 0)      { src = Wq; dst = wqkv; }
      else if (seg == 1) { src = Wk; dst = wqkv + 1048576; }
      else if (seg == 2) { src = Wv; dst = wqkv + 2097152; }
      else               { src = Wo; dst = wob; }
    }
    const float4* p = (const float4*)src + (size_t)o8 * 2;
    float4 a = p[0]; float4 b = p[1];
    f16x8 o;
    o[0]=(f16)a.x; o[1]=(f16)a.y; o[2]=(f16)a.z; o[3]=(f16)a.w;
    o[4]=(f16)b.x; o[5]=(f16)b.y; o[6]=(f16)b.z; o[7]=(f16)b.w;
    *(f16x8*)(dst + (size_t)o8 * 8) = o;
  }
}

// ---- C[M,N] = A[M,K]*B[N,K]^T + bias; 256^2 tile, BK=64, 8 waves (r7) ----
template<bool C_F32>
__global__ __launch_bounds__(512, 2) void k_gemm256(const f16* __restrict__ A,
                                                    const f16* __restrict__ B,
                                                    const float* __restrict__ b0,
                                                    const float* __restrict__ b1,
                                                    const float* __restrict__ b2,
                                                    void* __restrict__ Cout,
                                                    int M, int N, int K) {
  __shared__ f16 smem[2][2][2][128 * 64];   // [slot][A/B][half] = 128 KiB

  const int tid = threadIdx.x;
  const int lane = tid & 63;
  const int wid = tid >> 6;
  const int wr = wid >> 2;        // M-half
  const int wc = wid & 3;         // N-quarter
  const int lane_r = lane & 15;
  const int g = lane >> 4;

  // T1: XCD-aware swizzle (nwg % 8 == 0 by construction)
  const int nwg = gridDim.x;
  const int bid = blockIdx.x;
  const int swz = (bid & 7) * (nwg >> 3) + (bid >> 3);
  const int nbn = N >> 8;
  const int bm = swz / nbn, bn = swz % nbn;

  // swizzled frag-read offsets (16B units XORed with row&7; row&7 == lane_r&7)
  const int u0 = ((g) ^ (lane_r & 7)) * 8;
  const int u1 = ((4 + g) ^ (lane_r & 7)) * 8;
  // staging: lane covers LDS row l>>3, unit l&7; inverse-swizzled global unit
  const int arow = lane >> 3;
  const int acol = ((lane & 7) ^ (lane >> 3)) * 8;

  const f16* Ag[2] = { A + (size_t)(bm * 256) * K, A + (size_t)(bm * 256 + 128) * K };
  const f16* Bg[2] = { B + (size_t)(bn * 256) * K, B + (size_t)(bn * 256 + 128) * K };

  f32x4 acc[8][4];
#pragma unroll
  for (int i = 0; i < 8; ++i)
#pragma unroll
    for (int j = 0; j < 4; ++j) acc[i][j] = (f32x4){0.f, 0.f, 0.f, 0.f};

#define STAGE(gbase, kt, lbase)                                                     \
  {                                                                                 \
    _Pragma("unroll") for (int i_ = 0; i_ < 2; ++i_) {                              \
      const f16* g_ = (gbase) + (size_t)(wid * 16 + i_ * 8 + arow) * K + (kt) * 64 + acol; \
      __builtin_amdgcn_global_load_lds(                                             \
          (const __attribute__((address_space(1))) void*)g_,                        \
          (__attribute__((address_space(3))) void*)((lbase) + (wid * 16 + i_ * 8) * 64), \
          16, 0, 0);                                                                \
    }                                                                               \
  }

#define MFMAQ(q)                                                                    \
  _Pragma("unroll") for (int mm = 0; mm < 2; ++mm)                                  \
  _Pragma("unroll") for (int n = 0; n < 4; ++n) {                                   \
    acc[(q)*2 + mm][n] = __builtin_amdgcn_mfma_f32_16x16x32_f16(afrag[mm][0], bfrag[n][0], acc[(q)*2 + mm][n], 0, 0, 0); \
    acc[(q)*2 + mm][n] = __builtin_amdgcn_mfma_f32_16x16x32_f16(afrag[mm][1], bfrag[n][1], acc[(q)*2 + mm][n], 0, 0, 0); \
  }

#define READ_A(q)                                                                   \
  _Pragma("unroll") for (int mm = 0; mm < 2; ++mm) {                                \
    const int rb_ = ((q)*32 + mm * 16 + lane_r) * 64;                               \
    afrag[mm][0] = *(const f16x8*)&As_[rb_ + u0];                                   \
    afrag[mm][1] = *(const f16x8*)&As_[rb_ + u1];                                   \
  }

  // vm: vmcnt at tile entry. st: 2 = stage A(t+1)+B(t+2); 1 = A only; 0 = none
#define KTILE(t, slot, vm, st)                                                      \
  {                                                                                 \
    f16* As_ = smem[slot][0][wr];                                                   \
    f16* Bs_ = smem[slot][1][wc >> 1];                                              \
    f16x8 bfrag[4][2], afrag[2][2];                                                 \
    asm volatile("s_waitcnt vmcnt(%0)" :: "n"(vm) : "memory");                      \
    __builtin_amdgcn_s_barrier();                                                   \
    _Pragma("unroll") for (int n = 0; n < 4; ++n) {                                 \
      const int rb_ = ((wc & 1) * 64 + n * 16 + lane_r) * 64;                       \
      bfrag[n][0] = *(const f16x8*)&Bs_[rb_ + u0];                                  \
      bfrag[n][1] = *(const f16x8*)&Bs_[rb_ + u1];                                  \
    }                                                                               \
    READ_A(0)                                                                       \
    asm volatile("s_waitcnt lgkmcnt(4)" ::: "memory");                              \
    __builtin_amdgcn_s_barrier();                                                   \
    if ((st) >= 1) {                                                                \
      STAGE(Ag[0], (t) + 1, smem[(slot) ^ 1][0][0]);                                \
      STAGE(Ag[1], (t) + 1, smem[(slot) ^ 1][0][1]);                                \
    }                                                                               \
    if ((st) == 2) {                                                                \
      STAGE(Bg[0], (t) + 2, smem[slot][1][0]);                                      \
      STAGE(Bg[1], (t) + 2, smem[slot][1][1]);                                      \
    }                                                                               \
    __builtin_amdgcn_s_setprio(1);                                                  \
    MFMAQ(0)                                                                        \
    READ_A(1)                                                                       \
    MFMAQ(1)                                                                        \
    READ_A(2)                                                                       \
    MFMAQ(2)                                                                        \
    READ_A(3)                                                                       \
    MFMAQ(3)                                                                        \
    __builtin_amdgcn_s_setprio(0);                                                  \
  }

  const int nt = K >> 6;   // K-tiles (>= 4, even)

  // prologue: issue A_0 -> s0, B_0 -> s0, B_1 -> s1 (12 gloads; KTILE(0) waits)
  STAGE(Ag[0], 0, smem[0][0][0]);
  STAGE(Ag[1], 0, smem[0][0][1]);
  STAGE(Bg[0], 0, smem[0][1][0]);
  STAGE(Bg[1], 0, smem[0][1][1]);
  STAGE(Bg[0], 1, smem[1][1][0]);
  STAGE(Bg[1], 1, smem[1][1][1]);

  for (int t = 0; t + 3 < nt; t += 2) {
    KTILE(t, 0, 4, 2)
    KTILE(t + 1, 1, 4, 2)
  }
  KTILE(nt - 2, 0, 4, 1)
  KTILE(nt - 1, 1, 0, 0)

  // epilogue: C row = bm*256 + wr*128 + mrep*16 + (lane>>4)*4 + r ; col = bn*256 + wc*64 + n*16 + (lane&15)
  const int mrow0 = bm * 256 + wr * 128 + (lane >> 4) * 4;
  const int ncol0 = bn * 256 + wc * 64 + (lane & 15);
#pragma unroll
  for (int n = 0; n < 4; ++n) {
    const int col = ncol0 + n * 16;
    const float* bp = (col < 1024) ? b0 : ((col < 2048) ? b1 : b2);
    const float bvv = bp[col & 1023];
#pragma unroll
    for (int mrep = 0; mrep < 8; ++mrep) {
#pragma unroll
      for (int r = 0; r < 4; ++r) {
        const int row = mrow0 + mrep * 16 + r;
        const float val = acc[mrep][n][r] + bvv;
        if (C_F32) ((float*)Cout)[(size_t)row * N + col] = val;
        else       ((f16*)Cout)[(size_t)row * N + col] = (f16)val;
      }
    }
  }
#undef KTILE
#undef READ_A
#undef MFMAQ
#undef STAGE
}

// ------------------- axis attention: one block per (b,line) -----------------
// qkv layout: [32768 tokens][3072] with q at +0, k at +1024, v at +2048.
// r9: T14 V-prefetch (regs) + LDS transpose-out epilogue (coalesced stores).
template<bool IS_COL>
__global__ __launch_bounds__(256) void k_attn(const f16* __restrict__ qkv,
                                              f16* __restrict__ attn,
                                              const float* __restrict__ sigma) {
  __shared__ union {
    float S[64][68];                           // 17408 B (dead after softmax)
    struct { f16 Vt[256][72]; f16 O[64][264]; } pv;  // 36864 + 33792 = 70656 B
  } sm;
  __shared__ f16 P[64][72];                    // 9216 B ; total 79872 <= 80K

  const int tid = threadIdx.x;
  const int lane = tid & 63;
  const int wid = tid >> 6;
  const int blk = blockIdx.x;

  size_t tok0; int tstr;
  if (IS_COL) { tok0 = (size_t)(blk >> 6) * 4096 + (blk & 63); tstr = 64; }
  else        { tok0 = (size_t)blk * 64;                       tstr = 1;  }
  const size_t ibase = tok0 * 3072;  const int istr = tstr * 3072;
  const size_t obase = tok0 * 1024;  const int ostr = tstr * 1024;

  const float sg = sigma[0];
  const float gw = 0.5f / (sg * sg);

  const int m0 = wid * 16;
  const int lr = lane & 15;
  const int lq = lane >> 4;

  // ---- T14: issue chunk-0 V loads now; QK^T+softmax hide the latency ----
  const int kr = tid & 63;
  const int cg = tid >> 6;
  const f16* vp = qkv + ibase + 2048 + (size_t)kr * istr;
  f16x8 vreg[8];
#pragma unroll
  for (int j8 = 0; j8 < 8; ++j8)
    vreg[j8] = *(const f16x8*)(vp + cg * 64 + j8 * 8);

  // ---- phase A: S = Q K^T ----
  f32x4 sacc[4];
#pragma unroll
  for (int nt = 0; nt < 4; ++nt) sacc[nt] = (f32x4){0.f, 0.f, 0.f, 0.f};
  const f16* qp = qkv + ibase + (size_t)(m0 + lr) * istr + lq * 8;
  const f16* kp = qkv + ibase + 1024 + (size_t)lr * istr + lq * 8;
#pragma unroll 2
  for (int ks = 0; ks < 32; ++ks) {
    f16x8 af = *(const f16x8*)(qp + ks * 32);
#pragma unroll
    for (int nt = 0; nt < 4; ++nt) {
      f16x8 bfr = *(const f16x8*)(kp + (size_t)nt * 16 * istr + ks * 32);
      sacc[nt] = __builtin_amdgcn_mfma_f32_16x16x32_f16(af, bfr, sacc[nt], 0, 0, 0);
    }
  }
#pragma unroll
  for (int nt = 0; nt < 4; ++nt)
#pragma unroll
    for (int r = 0; r < 4; ++r) {
      const int row = m0 + lq * 4 + r;
      const int col = nt * 16 + lr;
      const float dd = (float)(row - col);
      sm.S[row][col] = sacc[nt][r] - gw * dd * dd;
    }
  __syncthreads();

  // ---- phase B: row softmax, 4 threads per row ----
  {
    const int r = tid >> 2, s4 = tid & 3;
    const float4* sp = (const float4*)&sm.S[r][s4 * 16];
    float vals[16];
#pragma unroll
    for (int j = 0; j < 4; ++j) {
      float4 t = sp[j];
      vals[j * 4 + 0] = t.x; vals[j * 4 + 1] = t.y; vals[j * 4 + 2] = t.z; vals[j * 4 + 3] = t.w;
    }
    float mx = vals[0];
#pragma unroll
    for (int j = 1; j < 16; ++j) mx = fmaxf(mx, vals[j]);
    mx = fmaxf(mx, __shfl_xor(mx, 1));
    mx = fmaxf(mx, __shfl_xor(mx, 2));
    float sum = 0.f;
#pragma unroll
    for (int j = 0; j < 16; ++j) { vals[j] = __expf(vals[j] - mx); sum += vals[j]; }
    sum += __shfl_xor(sum, 1);
    sum += __shfl_xor(sum, 2);
    const float inv = 1.f / sum;
#pragma unroll
    for (int j = 0; j < 16; ++j) P[r][s4 * 16 + j] = (f16)(vals[j] * inv);
  }
  __syncthreads();

  // ---- phase C: O = P V ; double-buffered V (regs), transpose-out epilogue ----
  const f16x8 af0 = *(const f16x8*)&P[m0 + lr][lq * 8];
  const f16x8 af1 = *(const f16x8*)&P[m0 + lr][32 + lq * 8];

  // scatter chunk 0 (S region dead; Vt lives in the union now)
#pragma unroll
  for (int j8 = 0; j8 < 8; ++j8) {
    const int cl = cg * 64 + j8 * 8;
#pragma unroll
    for (int e = 0; e < 8; ++e) sm.pv.Vt[cl + e][kr] = vreg[j8][e];
  }
  __syncthreads();

  for (int c = 0; c < 4; ++c) {
    // T14: issue next chunk's loads; they fly under this chunk's MFMA+epilogue
    if (c < 3) {
#pragma unroll
      for (int j8 = 0; j8 < 8; ++j8)
        vreg[j8] = *(const f16x8*)(vp + (c + 1) * 256 + cg * 64 + j8 * 8);
    }
    // MFMA on Vt(c); write O fragments to LDS (disjoint from Vt)
#pragma unroll
    for (int nt = 0; nt < 16; ++nt) {
      const f16x8 bf0 = *(const f16x8*)&sm.pv.Vt[nt * 16 + lr][lq * 8];
      const f16x8 bf1 = *(const f16x8*)&sm.pv.Vt[nt * 16 + lr][32 + lq * 8];
      f32x4 o = (f32x4){0.f, 0.f, 0.f, 0.f};
      o = __builtin_amdgcn_mfma_f32_16x16x32_f16(af0, bf0, o, 0, 0, 0);
      o = __builtin_amdgcn_mfma_f32_16x16x32_f16(af1, bf1, o, 0, 0, 0);
#pragma unroll
      for (int r = 0; r < 4; ++r)
        sm.pv.O[m0 + lq * 4 + r][nt * 16 + lr] = (f16)o[r];
    }
    __syncthreads();   // Vt reads done + O visible

    // coalesced store: thread t -> row t>>2, col-segment (t&3)*64 (128 B each)
    {
      const int orow = tid >> 2, cs = tid & 3;
      const size_t gaddr = obase + (size_t)orow * ostr + c * 256 + cs * 64;
#pragma unroll
      for (int j = 0; j < 8; ++j) {
        f16x8 ov = *(const f16x8*)&sm.pv.O[orow][cs * 64 + j * 8];
        if (IS_COL) {
          f16x8 old = *(const f16x8*)(attn + gaddr + j * 8);
#pragma unroll
          for (int e = 0; e < 8; ++e) ov[e] = (f16)((float)ov[e] + (float)old[e]);
        }
        *(f16x8*)(attn + gaddr + j * 8) = ov;
      }
    }
    // scatter next chunk (Vt free since the barrier above)
    if (c < 3) {
#pragma unroll
      for (int j8 = 0; j8 < 8; ++j8) {
        const int cl = cg * 64 + j8 * 8;
#pragma unroll
        for (int e = 0; e < 8; ++e) sm.pv.Vt[cl + e][kr] = vreg[j8][e];
      }
    }
    __syncthreads();   // Vt(c+1) visible + O reads done
  }
}

extern "C" void kernel_launch(void* const* d_in, const int* in_sizes, int n_in,
                              void* d_out, int out_size, void* d_ws, size_t ws_size,
                              hipStream_t stream) {
  const float* x  = (const float*)d_in[0];
  const float* Wq = (const float*)d_in[1];
  const float* bq = (const float*)d_in[2];
  const float* Wk = (const float*)d_in[3];
  const float* bk = (const float*)d_in[4];
  const float* Wv = (const float*)d_in[5];
  const float* bv = (const float*)d_in[6];
  const float* Wo = (const float*)d_in[7];
  const float* bo = (const float*)d_in[8];
  const float* sg = (const float*)d_in[9];

  const int M = 8 * 64 * 64;          // 32768 tokens
  const size_t NE = (size_t)M * 1024;

  f16* xb   = (f16*)d_ws;             // reused as attn buffer after QKV
  f16* wqkv = xb + NE;                // [3072][1024]
  f16* wob  = wqkv + 3 * 1024 * 1024; // [1024][1024]
  f16* qkv  = wob + 1024 * 1024;      // [32768][3072]

  k_cvt_all<<<2048, 256, 0, stream>>>(x, Wq, Wk, Wv, Wo, xb, wqkv, wob);

  // fused QKV GEMM: [32768,1024] x [3072,1024]^T -> [32768,3072]
  k_gemm256<false><<<(M / 256) * (3072 / 256), 512, 0, stream>>>(
      xb, wqkv, bq, bk, bv, qkv, M, 3072, 1024);

  f16* attn = xb;                     // x_f16 dead after QKV GEMM
  k_attn<false><<<512, 256, 0, stream>>>(qkv, attn, sg);  // row: writes
  k_attn<true><<<512, 256, 0, stream>>>(qkv, attn, sg);   // col: accumulates

  // output GEMM: [32768,1024] x [1024,1024]^T -> f32 out
  k_gemm256<true><<<(M / 256) * (1024 / 256), 512, 0, stream>>>(
      attn, wob, bo, bo, bo, (float*)d_out, M, 1024, 1024);
}